// Round 9
// baseline (92.063 us; speedup 1.0000x reference)
//
#include <hip/hip_runtime.h>
#include <hip/hip_bf16.h>

using bf16x8 = __attribute__((ext_vector_type(8))) __bf16;
using f32x4  = __attribute__((ext_vector_type(4))) float;
using f32x16 = __attribute__((ext_vector_type(16))) float;

#define MTOT   16384
#define DMODEL 1024
#define DSTATE 64
#define KBIG   1088

__device__ __forceinline__ ushort f2b(float f) {
  __hip_bfloat16 h = __float2bfloat16(f);
  return *reinterpret_cast<ushort*>(&h);
}

// async global->LDS, 16 bytes per lane. LDS dest = wave-uniform base + lane*16.
__device__ __forceinline__ void gld_lds16(const ushort* g, const char* l) {
  using gptr_t = const __attribute__((address_space(1))) uint32_t*;
  using lptr_t = __attribute__((address_space(3))) uint32_t*;
  __builtin_amdgcn_global_load_lds(
      reinterpret_cast<gptr_t>(reinterpret_cast<uintptr_t>(g)),
      reinterpret_cast<lptr_t>(static_cast<uint32_t>(reinterpret_cast<uintptr_t>(l))),
      16, 0, 0);
}

#define BARRIER() do { asm volatile("" ::: "memory"); __builtin_amdgcn_s_barrier(); asm volatile("" ::: "memory"); } while (0)
#define VMCNT8() asm volatile("s_waitcnt vmcnt(8)" ::: "memory")
#define VMCNT0() asm volatile("s_waitcnt vmcnt(0)" ::: "memory")

// ---------------- prep params ----------------
__global__ void prep_params(const float* __restrict__ A_diag, const float* __restrict__ B,
                            const float* __restrict__ C, const float* __restrict__ D,
                            ushort* __restrict__ Wt, ushort* __restrict__ Btu,
                            float* __restrict__ aSig) {
  int i = blockIdx.x * blockDim.x + threadIdx.x;
  int stride = gridDim.x * blockDim.x;
  for (int idx = i; idx < DMODEL * KBIG; idx += stride) {
    int n = idx / KBIG, k = idx % KBIG;
    float v = (k < DSTATE) ? C[k * DMODEL + n] : D[(size_t)(k - DSTATE) * DMODEL + n];
    Wt[idx] = f2b(v);
  }
  for (int idx = i; idx < DSTATE * DMODEL; idx += stride) {
    int s = idx >> 10, k = idx & 1023;
    Btu[idx] = f2b(B[k * DSTATE + s]);
  }
  if (i < DSTATE) aSig[i] = 1.0f / (1.0f + expf(-A_diag[i]));
}

// ---------------- fused: x -> Z(bf16), u = x@B -> chunk-local scan -> Uloc, carry ---------
__global__ __launch_bounds__(256) void fused_xu(const float* __restrict__ x,
    const ushort* __restrict__ Btu, const float* __restrict__ aSig,
    ushort* __restrict__ Z, float* __restrict__ Uloc, float* __restrict__ carry) {
  __shared__ ushort As[64][136];
  __shared__ float  Ul[64][68];
  int tid = threadIdx.x;
  int w = tid >> 6, lane = tid & 63;
  int l16 = lane & 15, lh = lane >> 4;
  int row0 = blockIdx.x * 64;

  f32x4 acc[4] = {};
  float4 xv[4][2];
#pragma unroll
  for (int p = 0; p < 4; ++p) {
    int fi = p * 256 + tid;
    int r = fi >> 4, kq = fi & 15;
    const float* src = x + (size_t)(row0 + r) * 1024 + kq * 8;
    xv[p][0] = *reinterpret_cast<const float4*>(src);
    xv[p][1] = *reinterpret_cast<const float4*>(src + 4);
  }
  for (int c = 0; c < 8; ++c) {
    int k0 = c * 128;
#pragma unroll
    for (int p = 0; p < 4; ++p) {
      int fi = p * 256 + tid;
      int r = fi >> 4, kq = fi & 15;
      ushort o[8] = {f2b(xv[p][0].x), f2b(xv[p][0].y), f2b(xv[p][0].z), f2b(xv[p][0].w),
                     f2b(xv[p][1].x), f2b(xv[p][1].y), f2b(xv[p][1].z), f2b(xv[p][1].w)};
      uint4 pk = *reinterpret_cast<uint4*>(o);
      *reinterpret_cast<uint4*>(&Z[(size_t)(row0 + r) * KBIG + DSTATE + k0 + kq * 8]) = pk;
      *reinterpret_cast<uint4*>(&As[r][kq * 8]) = pk;
    }
    __syncthreads();
    if (c < 7) {
      int k1 = k0 + 128;
#pragma unroll
      for (int p = 0; p < 4; ++p) {
        int fi = p * 256 + tid;
        int r = fi >> 4, kq = fi & 15;
        const float* src = x + (size_t)(row0 + r) * 1024 + k1 + kq * 8;
        xv[p][0] = *reinterpret_cast<const float4*>(src);
        xv[p][1] = *reinterpret_cast<const float4*>(src + 4);
      }
    }
#pragma unroll
    for (int ks = 0; ks < 4; ++ks) {
      bf16x8 af = *reinterpret_cast<const bf16x8*>(&As[w * 16 + l16][ks * 32 + lh * 8]);
#pragma unroll
      for (int n = 0; n < 4; ++n) {
        bf16x8 bf = *reinterpret_cast<const bf16x8*>(
            &Btu[(size_t)(n * 16 + l16) * 1024 + k0 + ks * 32 + lh * 8]);
        acc[n] = __builtin_amdgcn_mfma_f32_16x16x32_bf16(af, bf, acc[n], 0, 0, 0);
      }
    }
    __syncthreads();
  }
#pragma unroll
  for (int n = 0; n < 4; ++n)
#pragma unroll
    for (int j = 0; j < 4; ++j)
      Ul[w * 16 + lh * 4 + j][n * 16 + l16] = acc[n][j];
  __syncthreads();
  int s = lane;
  float as = aSig[s];
  float h = 0.0f;
  int g = blockIdx.x * 4 + w;
#pragma unroll
  for (int i = 0; i < 16; ++i) {
    h = fmaf(as, h, Ul[w * 16 + i][s]);
    Uloc[(size_t)(g * 16 + i) * 64 + s] = h;
  }
  carry[(size_t)g * 64 + s] = h;
}

// ---------------- hierarchical carry scan ----------------
__global__ __launch_bounds__(256) void carry_scan(const float* __restrict__ aSig,
    const float* __restrict__ carry, float* __restrict__ Hpref) {
  int b = threadIdx.x >> 6, s = threadIdx.x & 63;
  float as = aSig[s];
  float aL = as;
#pragma unroll
  for (int q = 0; q < 4; ++q) aL *= aL;  // as^16
  const float* cb = carry + ((size_t)b * 256) * 64 + s;
  float* hp = Hpref + ((size_t)b * 256) * 64 + s;
  float H = 0.0f;
  for (int c0 = 0; c0 < 256; c0 += 16) {
    float v[16];
#pragma unroll
    for (int i = 0; i < 16; ++i) v[i] = cb[(size_t)(c0 + i) * 64];
#pragma unroll
    for (int i = 0; i < 16; ++i) {
      hp[(size_t)(c0 + i) * 64] = H;
      H = fmaf(aL, H, v[i]);
    }
  }
}

// ---------------- scan fix ----------------
__global__ __launch_bounds__(256) void scan_fix2(const float* __restrict__ aSig,
    const float* __restrict__ Uloc, const float* __restrict__ Hpref,
    ushort* __restrict__ Z) {
  int w = threadIdx.x >> 6, s = threadIdx.x & 63;
  int g = blockIdx.x * 4 + w;
  float as = aSig[s];
  float H = Hpref[(size_t)g * 64 + s];
  float p = as;
  size_t ubase = (size_t)g * 16 * 64 + s;
  size_t zbase = (size_t)(g * 16) * KBIG + s;
#pragma unroll
  for (int i = 0; i < 16; ++i) {
    float h = fmaf(p, H, Uloc[ubase + (size_t)i * 64]);
    p *= as;
    Z[zbase + (size_t)i * KBIG] = f2b(h);
  }
}

// ---------------- 256x256 GEMM, 32x32x16 MFMA, 4 ks-phases/tile: y = Z @ Wt^T --------
// 8 waves (2x4), per-wave 128x64. 2 LDS bufs x 64KB = 128 KiB.
// Phase = {issue next-ks frag reads (6 x ds_read_b128); BARRIER; 8 MFMA} — reads
// stay in flight across the barrier (counted lgkm by compiler). All 8 stage
// gld_lds at ph3 after the ks3-read barrier; vmcnt(8) counted, never 0 mid-loop.
// Frag dbuf = 48 VGPR + acc 128 AGPR: fits default budget, no spill.
// Read swizzle: addr = base ^ (ks<<5) where base has slot (kh ^ (l32&7)); matches
// the stage-side pre-swizzled global source (slot ^ row&7).
__global__ __launch_bounds__(512) void gemm256(const ushort* __restrict__ A, int lda,
                                               const ushort* __restrict__ Bt, int ldb,
                                               float* __restrict__ Cc, int ldc, int K) {
  extern __shared__ __align__(128) char smem[];
  const int tid = threadIdx.x;
  const int wid = tid >> 6, lane = tid & 63;
  const int wm = wid >> 2, wn = wid & 3;
  const int l32 = lane & 31, kh = lane >> 5;

  int bid = blockIdx.x;
  int swz = (bid & 7) * ((int)gridDim.x >> 3) + (bid >> 3);
  const int bmRow = (swz >> 2) * 256;
  const int bnCol = (swz & 3) * 256;
  const int NT = K / 64;   // >= 3 (here 17)

  const int sRow = lane >> 3;
  const int sCol = (((lane & 7) ^ (lane >> 3)) << 3);

  const ushort* aBase = A + (size_t)(bmRow + wid * 8 + sRow) * lda + sCol;
  const ushort* bBase = Bt + (size_t)(bnCol + wid * 8 + sRow) * ldb + sCol;
  char* aDst0 = smem + (wid * 8) * 128;
  char* bDst0 = smem + 32768 + (wid * 8) * 128;

  // per-thread read bases (byte offset in buffer), slot pre-swizzled for ks=0
  const int aRB = (wm * 128 + l32) * 128 + ((kh ^ (l32 & 7)) << 4);
  const int bRB = 32768 + (wn * 64 + l32) * 128 + ((kh ^ (l32 & 7)) << 4);

  f32x16 acc[4][2] = {};
  bf16x8 aC[4], bC[2], aN[4], bN[2];

  auto stageA = [&](int buf, int t, int h) {  // half h: rows h*128..h*128+127
    const ushort* g0 = aBase + (size_t)(h * 128) * lda + (size_t)t * 64;
    const char* d = aDst0 + buf + h * 128 * 128;
    gld_lds16(g0, d);
    gld_lds16(g0 + (size_t)64 * lda, d + 64 * 128);
  };
  auto stageB = [&](int buf, int t, int h) {
    const ushort* g0 = bBase + (size_t)(h * 128) * ldb + (size_t)t * 64;
    const char* d = bDst0 + buf + h * 128 * 128;
    gld_lds16(g0, d);
    gld_lds16(g0 + (size_t)64 * ldb, d + 64 * 128);
  };
  auto readA = [&](bf16x8 (&d)[4], int buf, int ks) {
#pragma unroll
    for (int mb = 0; mb < 4; ++mb)
      d[mb] = *reinterpret_cast<const bf16x8*>(smem + buf + ((aRB + mb * 4096) ^ (ks << 5)));
  };
  auto readB = [&](bf16x8 (&d)[2], int buf, int ks) {
#pragma unroll
    for (int qn = 0; qn < 2; ++qn)
      d[qn] = *reinterpret_cast<const bf16x8*>(smem + buf + ((bRB + qn * 4096) ^ (ks << 5)));
  };
  auto mfmaC = [&](bf16x8 (&a4)[4], bf16x8 (&b2)[2]) {
    __builtin_amdgcn_s_setprio(1);
#pragma unroll
    for (int mb = 0; mb < 4; ++mb)
#pragma unroll
      for (int qn = 0; qn < 2; ++qn)
        acc[mb][qn] = __builtin_amdgcn_mfma_f32_32x32x16_bf16(
            a4[mb], b2[qn], acc[mb][qn], 0, 0, 0);
    __builtin_amdgcn_s_setprio(0);
  };

  // prologue: stage tiles 0 (buf0) and 1 (buf1); drain tile0, keep tile1 in flight
  stageA(0, 0, 0); stageA(0, 0, 1); stageB(0, 0, 0); stageB(0, 0, 1);
  stageA(65536, 1, 0); stageA(65536, 1, 1); stageB(65536, 1, 0); stageB(65536, 1, 1);
  VMCNT8();
  BARRIER();
  readA(aC, 0, 0); readB(bC, 0, 0);

  for (int t = 0; t < NT; ++t) {
    const int buf = (t & 1) << 16;
    const bool st2 = (t + 2 < NT);
    const bool nxt = (t + 1 < NT);
    // ph0
    readA(aN, buf, 1); readB(bN, buf, 1);
    BARRIER();
    mfmaC(aC, bC);
    // ph1
    readA(aC, buf, 2); readB(bC, buf, 2);
    BARRIER();
    mfmaC(aN, bN);
    // ph2
    readA(aN, buf, 3); readB(bN, buf, 3);
    BARRIER();
    mfmaC(aC, bC);
    // ph3: all current-buf reads issued (pre ph2-barrier) -> safe to restage
    if (st2) {
      stageA(buf, t + 2, 0); stageA(buf, t + 2, 1);
      stageB(buf, t + 2, 0); stageB(buf, t + 2, 1);
      VMCNT8();            // drains tile t+1's 8 stages; leaves t+2's in flight
    } else {
      VMCNT0();
    }
    BARRIER();             // publish buf^1 (tile t+1)
    if (nxt) { readA(aC, buf ^ 65536, 0); readB(bC, buf ^ 65536, 0); }
    mfmaC(aN, bN);
  }

  // epilogue: C/D 32x32 layout: col = lane&31, row = (reg&3) + 8*(reg>>2) + 4*(lane>>5)
#pragma unroll
  for (int mb = 0; mb < 4; ++mb)
#pragma unroll
    for (int qn = 0; qn < 2; ++qn)
#pragma unroll
      for (int reg = 0; reg < 16; ++reg) {
        int r = bmRow + wm * 128 + mb * 32 + (reg & 3) + 8 * (reg >> 2) + 4 * kh;
        int c = bnCol + wn * 64 + qn * 32 + l32;
        Cc[(size_t)r * ldc + c] = acc[mb][qn][reg];
      }
}

extern "C" void kernel_launch(void* const* d_in, const int* in_sizes, int n_in,
                              void* d_out, int out_size, void* d_ws, size_t ws_size,
                              hipStream_t stream) {
  const float* x      = (const float*)d_in[0];
  const float* A_diag = (const float*)d_in[1];
  const float* B      = (const float*)d_in[2];
  const float* C      = (const float*)d_in[3];
  const float* D      = (const float*)d_in[4];
  float* y = (float*)d_out;

  char* w = (char*)d_ws;
  ushort* Z     = (ushort*)(w);                 // [16384][1088] bf16  35,651,584
  ushort* Wt    = (ushort*)(w + 35651584);      // [1024][1088] bf16    2,228,224
  ushort* Btu   = (ushort*)(w + 37879808);      // [64][1024] bf16        131,072
  float*  Uloc  = (float*) (w + 38010880);      // [16384][64] f32      4,194,304
  float*  carry = (float*) (w + 42205184);      // [1024][64] f32         262,144
  float*  Hpref = (float*) (w + 42467328);      // [1024][64] f32         262,144
  float*  aSig  = (float*) (w + 42729472);      // [64] f32

  (void)hipFuncSetAttribute(reinterpret_cast<const void*>(&gemm256),
                            hipFuncAttributeMaxDynamicSharedMemorySize, 131072);

  prep_params<<<dim3(1024), dim3(256), 0, stream>>>(A_diag, B, C, D, Wt, Btu, aSig);
  fused_xu<<<dim3(256), dim3(256), 0, stream>>>(x, Btu, aSig, Z, Uloc, carry);
  carry_scan<<<dim3(1), dim3(256), 0, stream>>>(aSig, carry, Hpref);
  scan_fix2<<<dim3(256), dim3(256), 0, stream>>>(aSig, Uloc, Hpref, Z);
  // y = [h|x] @ [C;D] : M=16384, N=1024, K=1088  (256x256 tiles -> 256 blocks)
  gemm256<<<dim3(64 * 4), dim3(512), 131072, stream>>>(Z, KBIG, Wt, KBIG, y, DMODEL, KBIG);
}

// Round 10
// 89.006 us; speedup vs baseline: 1.0343x; 1.0343x over previous
//
#include <hip/hip_runtime.h>
#include <hip/hip_bf16.h>

using bf16x8 = __attribute__((ext_vector_type(8))) __bf16;
using f32x4  = __attribute__((ext_vector_type(4))) float;
using f32x16 = __attribute__((ext_vector_type(16))) float;

#define MTOT   16384
#define DMODEL 1024
#define DSTATE 64
#define KBIG   1088

__device__ __forceinline__ ushort f2b(float f) {
  __hip_bfloat16 h = __float2bfloat16(f);
  return *reinterpret_cast<ushort*>(&h);
}

// async global->LDS, 16 bytes per lane. LDS dest = wave-uniform base + lane*16.
__device__ __forceinline__ void gld_lds16(const ushort* g, const char* l) {
  using gptr_t = const __attribute__((address_space(1))) uint32_t*;
  using lptr_t = __attribute__((address_space(3))) uint32_t*;
  __builtin_amdgcn_global_load_lds(
      reinterpret_cast<gptr_t>(reinterpret_cast<uintptr_t>(g)),
      reinterpret_cast<lptr_t>(static_cast<uint32_t>(reinterpret_cast<uintptr_t>(l))),
      16, 0, 0);
}

#define BARRIER() do { asm volatile("" ::: "memory"); __builtin_amdgcn_s_barrier(); asm volatile("" ::: "memory"); } while (0)
#define VMCNT8() asm volatile("s_waitcnt vmcnt(8)" ::: "memory")
#define VMCNT0() asm volatile("s_waitcnt vmcnt(0)" ::: "memory")

// ---------------- prep params ----------------
__global__ void prep_params(const float* __restrict__ A_diag, const float* __restrict__ B,
                            const float* __restrict__ C, const float* __restrict__ D,
                            ushort* __restrict__ Wt, ushort* __restrict__ Btu,
                            float* __restrict__ aSig) {
  int i = blockIdx.x * blockDim.x + threadIdx.x;
  int stride = gridDim.x * blockDim.x;
  for (int idx = i; idx < DMODEL * KBIG; idx += stride) {
    int n = idx / KBIG, k = idx % KBIG;
    float v = (k < DSTATE) ? C[k * DMODEL + n] : D[(size_t)(k - DSTATE) * DMODEL + n];
    Wt[idx] = f2b(v);
  }
  for (int idx = i; idx < DSTATE * DMODEL; idx += stride) {
    int s = idx >> 10, k = idx & 1023;
    Btu[idx] = f2b(B[k * DSTATE + s]);
  }
  if (i < DSTATE) aSig[i] = 1.0f / (1.0f + expf(-A_diag[i]));
}

// ---------------- fused: x -> Z(bf16), u = x@B -> chunk-local scan -> Uloc, carry ---------
__global__ __launch_bounds__(256) void fused_xu(const float* __restrict__ x,
    const ushort* __restrict__ Btu, const float* __restrict__ aSig,
    ushort* __restrict__ Z, float* __restrict__ Uloc, float* __restrict__ carry) {
  __shared__ ushort As[64][136];
  __shared__ float  Ul[64][68];
  int tid = threadIdx.x;
  int w = tid >> 6, lane = tid & 63;
  int l16 = lane & 15, lh = lane >> 4;
  int row0 = blockIdx.x * 64;

  f32x4 acc[4] = {};
  float4 xv[4][2];
#pragma unroll
  for (int p = 0; p < 4; ++p) {
    int fi = p * 256 + tid;
    int r = fi >> 4, kq = fi & 15;
    const float* src = x + (size_t)(row0 + r) * 1024 + kq * 8;
    xv[p][0] = *reinterpret_cast<const float4*>(src);
    xv[p][1] = *reinterpret_cast<const float4*>(src + 4);
  }
  for (int c = 0; c < 8; ++c) {
    int k0 = c * 128;
#pragma unroll
    for (int p = 0; p < 4; ++p) {
      int fi = p * 256 + tid;
      int r = fi >> 4, kq = fi & 15;
      ushort o[8] = {f2b(xv[p][0].x), f2b(xv[p][0].y), f2b(xv[p][0].z), f2b(xv[p][0].w),
                     f2b(xv[p][1].x), f2b(xv[p][1].y), f2b(xv[p][1].z), f2b(xv[p][1].w)};
      uint4 pk = *reinterpret_cast<uint4*>(o);
      *reinterpret_cast<uint4*>(&Z[(size_t)(row0 + r) * KBIG + DSTATE + k0 + kq * 8]) = pk;
      *reinterpret_cast<uint4*>(&As[r][kq * 8]) = pk;
    }
    __syncthreads();
    if (c < 7) {
      int k1 = k0 + 128;
#pragma unroll
      for (int p = 0; p < 4; ++p) {
        int fi = p * 256 + tid;
        int r = fi >> 4, kq = fi & 15;
        const float* src = x + (size_t)(row0 + r) * 1024 + k1 + kq * 8;
        xv[p][0] = *reinterpret_cast<const float4*>(src);
        xv[p][1] = *reinterpret_cast<const float4*>(src + 4);
      }
    }
#pragma unroll
    for (int ks = 0; ks < 4; ++ks) {
      bf16x8 af = *reinterpret_cast<const bf16x8*>(&As[w * 16 + l16][ks * 32 + lh * 8]);
#pragma unroll
      for (int n = 0; n < 4; ++n) {
        bf16x8 bf = *reinterpret_cast<const bf16x8*>(
            &Btu[(size_t)(n * 16 + l16) * 1024 + k0 + ks * 32 + lh * 8]);
        acc[n] = __builtin_amdgcn_mfma_f32_16x16x32_bf16(af, bf, acc[n], 0, 0, 0);
      }
    }
    __syncthreads();
  }
#pragma unroll
  for (int n = 0; n < 4; ++n)
#pragma unroll
    for (int j = 0; j < 4; ++j)
      Ul[w * 16 + lh * 4 + j][n * 16 + l16] = acc[n][j];
  __syncthreads();
  int s = lane;
  float as = aSig[s];
  float h = 0.0f;
  int g = blockIdx.x * 4 + w;
#pragma unroll
  for (int i = 0; i < 16; ++i) {
    h = fmaf(as, h, Ul[w * 16 + i][s]);
    Uloc[(size_t)(g * 16 + i) * 64 + s] = h;
  }
  carry[(size_t)g * 64 + s] = h;
}

// ---------------- scan fix (merged): redundant batched prefix + apply + write Z ------
// Wave g: exclusive prefix H over carries of chunks [b*256, g) with decay aL=as^16,
// loads batched 16-wide (independent), predication wave-uniform. Then apply.
__global__ __launch_bounds__(256) void scan_fix2(const float* __restrict__ aSig,
    const float* __restrict__ Uloc, const float* __restrict__ carry,
    ushort* __restrict__ Z) {
  int w = threadIdx.x >> 6, s = threadIdx.x & 63;
  int g = blockIdx.x * 4 + w;          // 0..1023
  int b = g >> 8, c = g & 255;
  float as = aSig[s];
  float aL = as;
#pragma unroll
  for (int q = 0; q < 4; ++q) aL *= aL;  // as^16
  const float* cb = carry + ((size_t)b << 8) * 64 + s;
  float H = 0.0f;
  for (int c0 = 0; c0 < 256; c0 += 16) {
    if (c0 >= c) break;                  // wave-uniform
    float v[16];
#pragma unroll
    for (int i = 0; i < 16; ++i) v[i] = cb[(size_t)(c0 + i) * 64];
#pragma unroll
    for (int i = 0; i < 16; ++i)
      if (c0 + i < c) H = fmaf(aL, H, v[i]);   // wave-uniform predicate
  }
  float p = as;
  size_t ubase = (size_t)g * 16 * 64 + s;
  size_t zbase = (size_t)(g * 16) * KBIG + s;
#pragma unroll
  for (int i = 0; i < 16; ++i) {
    float h = fmaf(p, H, Uloc[ubase + (size_t)i * 64]);
    p *= as;
    Z[zbase + (size_t)i * KBIG] = f2b(h);
  }
}

// ---------------- 256x256 GEMM, 32x32x16 MFMA, 2 barriers/tile: y = Z @ Wt^T --------
// 8 waves (2x4), per-wave 128x64. 2 LDS bufs x 64KB = 128 KiB.
// Per tile: reads ks1..ks3 flow under mfma ks0..ks2 (same-wave lgkm deps only);
// B1 after all reads issued -> batch-stage t+2 into current buf -> vmcnt(8)
// (drains t+1's stages, leaves t+2's in flight; 0 only at tail) -> B2 publish
// -> read ks0 of next buf -> mfma ks3. Frag dbuf 48 VGPR + acc 128 AGPR: no spill.
__global__ __launch_bounds__(512) void gemm256(const ushort* __restrict__ A, int lda,
                                               const ushort* __restrict__ Bt, int ldb,
                                               float* __restrict__ Cc, int ldc, int K) {
  extern __shared__ __align__(128) char smem[];
  const int tid = threadIdx.x;
  const int wid = tid >> 6, lane = tid & 63;
  const int wm = wid >> 2, wn = wid & 3;
  const int l32 = lane & 31, kh = lane >> 5;

  int bid = blockIdx.x;
  int swz = (bid & 7) * ((int)gridDim.x >> 3) + (bid >> 3);
  const int bmRow = (swz >> 2) * 256;
  const int bnCol = (swz & 3) * 256;
  const int NT = K / 64;   // >= 3 (here 17)

  const int sRow = lane >> 3;
  const int sCol = (((lane & 7) ^ (lane >> 3)) << 3);

  const ushort* aBase = A + (size_t)(bmRow + wid * 8 + sRow) * lda + sCol;
  const ushort* bBase = Bt + (size_t)(bnCol + wid * 8 + sRow) * ldb + sCol;
  char* aDst0 = smem + (wid * 8) * 128;
  char* bDst0 = smem + 32768 + (wid * 8) * 128;

  const int aRB = (wm * 128 + l32) * 128 + ((kh ^ (l32 & 7)) << 4);
  const int bRB = 32768 + (wn * 64 + l32) * 128 + ((kh ^ (l32 & 7)) << 4);

  f32x16 acc[4][2] = {};
  bf16x8 aC[4], bC[2], aN[4], bN[2];

  auto stageA = [&](int buf, int t, int h) {
    const ushort* g0 = aBase + (size_t)(h * 128) * lda + (size_t)t * 64;
    const char* d = aDst0 + buf + h * 128 * 128;
    gld_lds16(g0, d);
    gld_lds16(g0 + (size_t)64 * lda, d + 64 * 128);
  };
  auto stageB = [&](int buf, int t, int h) {
    const ushort* g0 = bBase + (size_t)(h * 128) * ldb + (size_t)t * 64;
    const char* d = bDst0 + buf + h * 128 * 128;
    gld_lds16(g0, d);
    gld_lds16(g0 + (size_t)64 * ldb, d + 64 * 128);
  };
  auto readA = [&](bf16x8 (&d)[4], int buf, int ks) {
#pragma unroll
    for (int mb = 0; mb < 4; ++mb)
      d[mb] = *reinterpret_cast<const bf16x8*>(smem + buf + ((aRB + mb * 4096) ^ (ks << 5)));
  };
  auto readB = [&](bf16x8 (&d)[2], int buf, int ks) {
#pragma unroll
    for (int qn = 0; qn < 2; ++qn)
      d[qn] = *reinterpret_cast<const bf16x8*>(smem + buf + ((bRB + qn * 4096) ^ (ks << 5)));
  };
  auto mfmaC = [&](bf16x8 (&a4)[4], bf16x8 (&b2)[2]) {
    __builtin_amdgcn_s_setprio(1);
#pragma unroll
    for (int mb = 0; mb < 4; ++mb)
#pragma unroll
      for (int qn = 0; qn < 2; ++qn)
        acc[mb][qn] = __builtin_amdgcn_mfma_f32_32x32x16_bf16(
            a4[mb], b2[qn], acc[mb][qn], 0, 0, 0);
    __builtin_amdgcn_s_setprio(0);
  };

  // prologue: stage tiles 0 (buf0) and 1 (buf1); drain tile0, keep tile1 in flight
  stageA(0, 0, 0); stageA(0, 0, 1); stageB(0, 0, 0); stageB(0, 0, 1);
  stageA(65536, 1, 0); stageA(65536, 1, 1); stageB(65536, 1, 0); stageB(65536, 1, 1);
  VMCNT8();
  BARRIER();
  readA(aC, 0, 0); readB(bC, 0, 0);

  for (int t = 0; t < NT; ++t) {
    const int buf = (t & 1) << 16;
    const bool st2 = (t + 2 < NT);
    const bool nxt = (t + 1 < NT);
    readA(aN, buf, 1); readB(bN, buf, 1);
    mfmaC(aC, bC);                       // ks0
    readA(aC, buf, 2); readB(bC, buf, 2);
    mfmaC(aN, bN);                       // ks1
    readA(aN, buf, 3); readB(bN, buf, 3);
    mfmaC(aC, bC);                       // ks2
    BARRIER();                           // B1: all reads of buf issued block-wide
    if (st2) {
      stageA(buf, t + 2, 0); stageA(buf, t + 2, 1);
      stageB(buf, t + 2, 0); stageB(buf, t + 2, 1);
      VMCNT8();                          // drains t+1's 8 stages; t+2's stay in flight
    } else {
      VMCNT0();
    }
    BARRIER();                           // B2: publish buf^1 (tile t+1)
    if (nxt) { readA(aC, buf ^ 65536, 0); readB(bC, buf ^ 65536, 0); }
    mfmaC(aN, bN);                       // ks3
  }

  // epilogue: C/D 32x32 layout: col = lane&31, row = (reg&3) + 8*(reg>>2) + 4*(lane>>5)
#pragma unroll
  for (int mb = 0; mb < 4; ++mb)
#pragma unroll
    for (int qn = 0; qn < 2; ++qn)
#pragma unroll
      for (int reg = 0; reg < 16; ++reg) {
        int r = bmRow + wm * 128 + mb * 32 + (reg & 3) + 8 * (reg >> 2) + 4 * kh;
        int c = bnCol + wn * 64 + qn * 32 + l32;
        Cc[(size_t)r * ldc + c] = acc[mb][qn][reg];
      }
}

extern "C" void kernel_launch(void* const* d_in, const int* in_sizes, int n_in,
                              void* d_out, int out_size, void* d_ws, size_t ws_size,
                              hipStream_t stream) {
  const float* x      = (const float*)d_in[0];
  const float* A_diag = (const float*)d_in[1];
  const float* B      = (const float*)d_in[2];
  const float* C      = (const float*)d_in[3];
  const float* D      = (const float*)d_in[4];
  float* y = (float*)d_out;

  char* w = (char*)d_ws;
  ushort* Z     = (ushort*)(w);                 // [16384][1088] bf16  35,651,584
  ushort* Wt    = (ushort*)(w + 35651584);      // [1024][1088] bf16    2,228,224
  ushort* Btu   = (ushort*)(w + 37879808);      // [64][1024] bf16        131,072
  float*  Uloc  = (float*) (w + 38010880);      // [16384][64] f32      4,194,304
  float*  carry = (float*) (w + 42205184);      // [1024][64] f32         262,144
  float*  aSig  = (float*) (w + 42467328);      // [64] f32

  (void)hipFuncSetAttribute(reinterpret_cast<const void*>(&gemm256),
                            hipFuncAttributeMaxDynamicSharedMemorySize, 131072);

  prep_params<<<dim3(1024), dim3(256), 0, stream>>>(A_diag, B, C, D, Wt, Btu, aSig);
  fused_xu<<<dim3(256), dim3(256), 0, stream>>>(x, Btu, aSig, Z, Uloc, carry);
  scan_fix2<<<dim3(256), dim3(256), 0, stream>>>(aSig, Uloc, carry, Z);
  // y = [h|x] @ [C;D] : M=16384, N=1024, K=1088  (256x256 tiles -> 256 blocks)
  gemm256<<<dim3(64 * 4), dim3(512), 131072, stream>>>(Z, KBIG, Wt, KBIG, y, DMODEL, KBIG);
}